// Round 10
// baseline (1515.327 us; speedup 1.0000x reference)
//
#include <hip/hip_runtime.h>
#include <math.h>

#define HID 256
#define LROW 40   // LDS row stride in bf16 elems (32 data + 8 pad) -> 80B

typedef __bf16 bf16x8 __attribute__((ext_vector_type(8)));
typedef float  f32x4  __attribute__((ext_vector_type(4)));
typedef unsigned short us8 __attribute__((ext_vector_type(8)));

__device__ __forceinline__ float sigmoidf_(float x){ return 1.0f/(1.0f + __expf(-x)); }
__device__ __forceinline__ unsigned short f2b(float f){
  __bf16 b = (__bf16)f; return __builtin_bit_cast(unsigned short, b);
}
__device__ __forceinline__ float b2f(unsigned short u){
  return (float)__builtin_bit_cast(__bf16, u);
}

// ---- edge index access: handles both int32 and int64 on-disk storage ----
__device__ __forceinline__ int edge_src(const int* ei, int e, int is64){
  return is64 ? ei[2*e] : ei[e];
}
__device__ __forceinline__ int edge_dst(const int* ei, int e, int E, int is64){
  return is64 ? ei[2*(E+e)] : ei[E+e];
}

__global__ void detect_kernel(const int* __restrict__ ei, int* __restrict__ flag){
  __shared__ int any;
  if (threadIdx.x == 0) any = 0;
  __syncthreads();
  if (ei[2*threadIdx.x + 1] != 0) atomicOr(&any, 1);
  __syncthreads();
  if (threadIdx.x == 0) *flag = any ? 0 : 1;   // 1 -> int64 storage
}

__global__ void count_kernel(const int* __restrict__ ei, const int* __restrict__ flag,
                             int* __restrict__ deg_i, int E){
  int e = blockIdx.x*blockDim.x + threadIdx.x;
  if (e >= E) return;
  int is64 = *flag;
  atomicAdd(&deg_i[edge_dst(ei,e,E,is64)], 1);
}

__global__ __launch_bounds__(1024) void scan_kernel(const int* __restrict__ deg_i,
  int* __restrict__ row_ptr, float* __restrict__ inv_deg, int N)
{
  __shared__ int wsum[16];
  __shared__ int carry_s;
  int tid = threadIdx.x, lane = tid & 63, wid = tid >> 6;
  if (tid == 0) carry_s = 0;
  __syncthreads();
  for (int base = 0; base < N; base += 1024){
    int i = base + tid;
    int v = (i < N) ? deg_i[i] : 0;
    int s = v;
    #pragma unroll
    for (int off = 1; off < 64; off <<= 1){
      int t = __shfl_up(s, off, 64);
      if (lane >= off) s += t;
    }
    if (lane == 63) wsum[wid] = s;
    __syncthreads();
    if (tid == 0){
      int run = 0;
      for (int w2 = 0; w2 < 16; ++w2){ int t = wsum[w2]; wsum[w2] = run; run += t; }
    }
    __syncthreads();
    int excl = carry_s + wsum[wid] + s - v;
    if (i < N){
      row_ptr[i] = excl;
      inv_deg[i] = 1.0f / fmaxf((float)v, 1.0f);
    }
    __syncthreads();
    if (tid == 1023) carry_s = excl + v;
    __syncthreads();
  }
  if (threadIdx.x == 0) row_ptr[N] = carry_s;
}

__global__ void fill_kernel(const int* __restrict__ ei, const int* __restrict__ flag,
                            const int* __restrict__ row_ptr, int* __restrict__ cursor,
                            int* __restrict__ col_src, int E){
  int e = blockIdx.x*blockDim.x + threadIdx.x;
  if (e >= E) return;
  int is64 = *flag;
  int d = edge_dst(ei,e,E,is64);
  int pos = atomicAdd(&cursor[d], 1);
  col_src[row_ptr[d] + pos] = edge_src(ei,e,is64);
}

// f32 -> bf16 conversion (vector of 4)
__global__ __launch_bounds__(256) void conv_kernel(const float* __restrict__ in,
                                                   unsigned short* __restrict__ out, int n4){
  int i = blockIdx.x*256 + threadIdx.x;
  if (i >= n4) return;
  float4 v = *(const float4*)&in[(size_t)i*4];
  ushort4 o; o.x=f2b(v.x); o.y=f2b(v.y); o.z=f2b(v.z); o.w=f2b(v.w);
  *(ushort4*)&out[(size_t)i*4] = o;
}

// weights: f32 [K][N] row-major -> bf16 [N][K] (transposed), 18 slabs of 256x256
__global__ __launch_bounds__(256) void wconv_kernel(
  const float* __restrict__ Wx_l, const float* __restrict__ Wx_r,
  const float* __restrict__ Wh_l, const float* __restrict__ Wh_r,
  const float* __restrict__ Wb1,  const float* __restrict__ Wb2,
  const float* __restrict__ We1,  unsigned short* __restrict__ Wt)
{
  int widx = blockIdx.x;       // 0..17
  int n = blockIdx.y;          // 0..255 (output row = W column)
  int k = threadIdx.x;         // 0..255
  const float* src;
  if      (widx < 3)  src = Wx_l + widx*65536;
  else if (widx < 6)  src = Wx_r + (widx-3)*65536;
  else if (widx < 10) src = Wh_l + (widx-6)*65536;
  else if (widx < 14) src = Wh_r + (widx-10)*65536;
  else if (widx == 14) src = Wb1;
  else if (widx == 15) src = Wb2;
  else                src = We1 + (widx-16)*65536;
  Wt[(size_t)widx*65536 + n*256 + k] = f2b(src[k*256 + n]);
}

// composite weight: dst[n][k] (bf16, transposed) = (A@B)[k][n] + add[k][n]
__global__ __launch_bounds__(256) void comp_kernel(
  const float* __restrict__ A, const float* __restrict__ B,
  const float* __restrict__ add, unsigned short* __restrict__ dst)
{
  __shared__ float col[256];
  int n = blockIdx.x, k = threadIdx.x;
  col[k] = B[k*256 + n];
  __syncthreads();
  float s = add ? add[k*256 + n] : 0.f;
  #pragma unroll 8
  for (int j = 0; j < 256; ++j) s = fmaf(A[k*256 + j], col[j], s);
  dst[n*256 + k] = f2b(s);
}

// mean aggregation over bf16 features: one wave per node, ushort4 per lane
__global__ __launch_bounds__(256) void aggregate_b_kernel(
    const unsigned short* __restrict__ X, unsigned short* __restrict__ out,
    const int* __restrict__ row_ptr, const int* __restrict__ col_src,
    const float* __restrict__ inv_deg, int N)
{
  int v = blockIdx.x*4 + (threadIdx.x >> 6);
  int lane = threadIdx.x & 63;
  if (v >= N) return;
  int beg = row_ptr[v], end = row_ptr[v+1];
  float a0=0.f, a1=0.f, a2=0.f, a3=0.f;
  int e = beg;
  for (; e + 8 <= end; e += 8){
    int sidx[8];
    #pragma unroll
    for (int t = 0; t < 8; ++t) sidx[t] = col_src[e + t];
    #pragma unroll
    for (int t = 0; t < 8; ++t){
      ushort4 u = *(const ushort4*)&X[(size_t)sidx[t]*HID + lane*4];
      a0 += b2f(u.x); a1 += b2f(u.y); a2 += b2f(u.z); a3 += b2f(u.w);
    }
  }
  for (; e < end; ++e){
    int s0 = col_src[e];
    ushort4 u = *(const ushort4*)&X[(size_t)s0*HID + lane*4];
    a0 += b2f(u.x); a1 += b2f(u.y); a2 += b2f(u.z); a3 += b2f(u.w);
  }
  float w = inv_deg[v];
  ushort4 o; o.x=f2b(a0*w); o.y=f2b(a1*w); o.z=f2b(a2*w); o.w=f2b(a3*w);
  *(ushort4*)&out[(size_t)v*HID + lane*4] = o;
}

// layer-1 constant rows (f32): brow = bb1+bb2+bh0@Wb2; hrow = tanh(brow); rowL/rowR for r,z
__global__ __launch_bounds__(256) void rowprep_kernel(
  const float* __restrict__ bh_l, const float* __restrict__ bb1, const float* __restrict__ bb2,
  const float* __restrict__ Wb2, const float* __restrict__ Wh_l, const float* __restrict__ Wh_r,
  float* __restrict__ brow, float* __restrict__ hrow,
  float* __restrict__ rowL1, float* __restrict__ rowR1,
  float* __restrict__ rowL2, float* __restrict__ rowR2)
{
  __shared__ float sh[256];
  __shared__ float sh2[256];
  int j = threadIdx.x;
  sh[j] = bh_l[j];                       // bh_l[0]
  __syncthreads();
  float acc = bb1[j] + bb2[j];
  for (int k = 0; k < 256; ++k) acc = fmaf(sh[k], Wb2[k*256 + j], acc);
  float hr = tanhf(acc);
  brow[j] = acc;
  hrow[j] = hr; sh2[j] = hr;
  __syncthreads();
  const float* Whl1 = Wh_l + 65536;  const float* Whr1 = Wh_r + 65536;
  const float* Whl2 = Wh_l + 131072; const float* Whr2 = Wh_r + 131072;
  float a1=0.f, b1=0.f, a2=0.f, b2v=0.f;
  for (int k = 0; k < 256; ++k){
    float hv = sh2[k];
    a1  = fmaf(hv, Whl1[k*256+j], a1);
    b1  = fmaf(hv, Whr1[k*256+j], b1);
    a2  = fmaf(hv, Whl2[k*256+j], a2);
    b2v = fmaf(hv, Whr2[k*256+j], b2v);
  }
  rowL1[j] = a1; rowR1[j] = b1 + bh_l[256 + j];
  rowL2[j] = a2; rowR2[j] = b2v + bh_l[512 + j];
}

// layer-1 elementwise (xc0/xc1 are hoisted x-projections, bf16):
// t1 = sigmoid(xc0 + g*rowL1 + rowR1)*hrow ; z1 = sigmoid(xc1 + g*rowL2 + rowR2)
__global__ __launch_bounds__(256) void l1_elem_kernel(
  const unsigned short* __restrict__ xc0, const unsigned short* __restrict__ xc1,
  const int* __restrict__ deg_i, const float* __restrict__ hrow,
  const float* __restrict__ rowL1, const float* __restrict__ rowR1,
  const float* __restrict__ rowL2, const float* __restrict__ rowR2,
  unsigned short* __restrict__ t1, float* __restrict__ z1, int N)
{
  int idx = blockIdx.x*256 + threadIdx.x;      // ushort4 index
  if (idx >= N*64) return;
  int v = idx >> 6, j4 = (idx & 63) * 4;
  float g = deg_i[v] > 0 ? 1.f : 0.f;
  ushort4 a = *(const ushort4*)&xc0[(size_t)idx*4];
  ushort4 b = *(const ushort4*)&xc1[(size_t)idx*4];
  float4 L1 = *(const float4*)&rowL1[j4];
  float4 R1 = *(const float4*)&rowR1[j4];
  float4 L2 = *(const float4*)&rowL2[j4];
  float4 R2 = *(const float4*)&rowR2[j4];
  float4 hr = *(const float4*)&hrow[j4];
  ushort4 t; float4 z;
  t.x = f2b(sigmoidf_(b2f(a.x) + g*L1.x + R1.x) * hr.x);
  t.y = f2b(sigmoidf_(b2f(a.y) + g*L1.y + R1.y) * hr.y);
  t.z = f2b(sigmoidf_(b2f(a.z) + g*L1.z + R1.z) * hr.z);
  t.w = f2b(sigmoidf_(b2f(a.w) + g*L1.w + R1.w) * hr.w);
  z.x = sigmoidf_(b2f(b.x) + g*L2.x + R2.x);
  z.y = sigmoidf_(b2f(b.y) + g*L2.y + R2.y);
  z.z = sigmoidf_(b2f(b.z) + g*L2.z + R2.z);
  z.w = sigmoidf_(b2f(b.w) + g*L2.w + R2.w);
  *(ushort4*)&t1[(size_t)idx*4] = t;
  *(float4*)&z1[(size_t)idx*4] = z;
}

// ---- fused MFMA GEMM: up to three independent jobs per dispatch (blockIdx.y) ----
struct GJob {
  const unsigned short *A0,*W0,*A1,*W1;
  const float *bias,*Z,*HN;
  const float *mulmat,*Df;
  const unsigned short *Db,*Zb;
  float* outF; unsigned short* outB;
  int hn_bcast;
};

// 128-row x 256-col tile (round-8 proven geometry), 512 threads (8 waves 2x4).
// Each block reads its A panel once; W panel amortized over 128 rows.
// pre = sum_i Ai@Wi^T + bias + Df + Db(bf16)
// MODE 0 LIN, 1 SIG(pre)*mulmat, 2 TANHADD: HN[idx]+tanh(pre), 3 GRU: (1-Z)*HN + Z*tanh(pre)
template<int MODE>
__global__ __launch_bounds__(512) void mgemm5_kernel(GJob j0, GJob j1, GJob j2, int M)
{
  __shared__ unsigned short Al[128*LROW];
  __shared__ unsigned short Wl[256*LROW];
  const GJob& J = (blockIdx.y == 0) ? j0 : ((blockIdx.y == 1) ? j1 : j2);
  const int tid  = threadIdx.x;
  const int lane = tid & 63, w = tid >> 6;     // 8 waves
  const int wr = w >> 2, wc = w & 3;           // 2 (row groups of 64) x 4 (col groups of 64)
  const int lane15 = lane & 15, laneq = (lane >> 4) * 8;
  const int row0 = blockIdx.x * 128;

  f32x4 acc[4][4];
  #pragma unroll
  for (int m = 0; m < 4; ++m)
    #pragma unroll
    for (int n = 0; n < 4; ++n) acc[m][n] = (f32x4)0.f;

  // compact pass list (up to 2 passes)
  const unsigned short* pa[2]; const unsigned short* pw[2];
  int np = 0;
  if (J.A0){ pa[np]=J.A0; pw[np]=J.W0; ++np; }
  if (J.A1){ pa[np]=J.A1; pw[np]=J.W1; ++np; }
  const int steps = np * 8;            // K=256, BK=32 -> always even

  // staging (round-8): A row tid>>2, 16B chunk (tid&3); W rows tid>>2 and +128, same chunk
  const int strow = tid >> 2;
  const int koff  = (tid & 3) * 8;     // element offset
  const int garow = (row0 + strow > M-1) ? (M-1) : (row0 + strow);
  const size_t abase  = (size_t)garow*HID + koff;
  const size_t wbase0 = (size_t)strow*HID + koff;
  const size_t wbase1 = (size_t)(strow + 128)*HID + koff;
  const int asidx  = strow*LROW + koff;
  const int wsidx0 = strow*LROW + koff;
  const int wsidx1 = (strow + 128)*LROW + koff;

  uint4 Ar0,Wr0a,Wr0b, Ar1,Wr1a,Wr1b;   // two static 2-deep prefetch sets
  auto loadR = [&](int sp, uint4& a, uint4& wa, uint4& wb){
    const unsigned short* Ap = pa[sp >> 3];
    const unsigned short* Wp = pw[sp >> 3];
    const int k0 = (sp & 7) * 32;
    a  = *(const uint4*)(Ap + abase  + k0);
    wa = *(const uint4*)(Wp + wbase0 + k0);
    wb = *(const uint4*)(Wp + wbase1 + k0);
  };
  auto compute = [&](){
    bf16x8 af[4], bfr[4];
    #pragma unroll
    for (int m = 0; m < 4; ++m)
      af[m] = *(const bf16x8*)&Al[(wr*64 + m*16 + lane15)*LROW + laneq];
    #pragma unroll
    for (int n = 0; n < 4; ++n)
      bfr[n] = *(const bf16x8*)&Wl[(wc*64 + n*16 + lane15)*LROW + laneq];
    #pragma unroll
    for (int m = 0; m < 4; ++m)
      #pragma unroll
      for (int n = 0; n < 4; ++n)
        acc[m][n] = __builtin_amdgcn_mfma_f32_16x16x32_bf16(af[m], bfr[n], acc[m][n], 0, 0, 0);
  };

  loadR(0, Ar0,Wr0a,Wr0b);
  loadR(1, Ar1,Wr1a,Wr1b);
  for (int s = 0; s < steps; s += 2){
    __syncthreads();
    *(uint4*)&Al[asidx]  = Ar0;
    *(uint4*)&Wl[wsidx0] = Wr0a;
    *(uint4*)&Wl[wsidx1] = Wr0b;
    __syncthreads();
    if (s + 2 < steps) loadR(s+2, Ar0,Wr0a,Wr0b);
    compute();
    __syncthreads();
    *(uint4*)&Al[asidx]  = Ar1;
    *(uint4*)&Wl[wsidx0] = Wr1a;
    *(uint4*)&Wl[wsidx1] = Wr1b;
    __syncthreads();
    if (s + 3 < steps) loadR(s+3, Ar1,Wr1a,Wr1b);
    compute();
  }

  // epilogue: D[row][col]: col = lane&15, row = (lane>>4)*4 + r
  #pragma unroll
  for (int n = 0; n < 4; ++n){
    int gc = wc*64 + n*16 + lane15;
    float badd = J.bias ? J.bias[gc] : 0.f;
    float hnb = 0.f;
    if (MODE == 3 && J.hn_bcast) hnb = J.HN[gc];
    #pragma unroll
    for (int m = 0; m < 4; ++m){
      int rbse = row0 + wr*64 + m*16 + ((lane >> 4) << 2);
      #pragma unroll
      for (int r = 0; r < 4; ++r){
        int gr = rbse + r;
        if (gr >= M) continue;
        size_t idx = (size_t)gr*HID + gc;
        float p = acc[m][n][r] + badd;
        if (J.Df) p += J.Df[idx];
        if (J.Db) p += b2f(J.Db[idx]);
        float v;
        if (MODE == 0) v = p;
        else if (MODE == 1){
          v = sigmoidf_(p);
          if (J.mulmat) v *= J.mulmat[idx];
        } else if (MODE == 2){
          v = J.HN[idx] + tanhf(p);
        } else {
          float z  = J.Z ? J.Z[idx] : b2f(J.Zb[idx]);
          float hv = J.hn_bcast ? hnb : J.HN[idx];
          v = (1.f - z)*hv + z*tanhf(p);
        }
        if (J.outF) J.outF[idx] = v;
        if (J.outB) J.outB[idx] = f2b(v);
      }
    }
  }
}

// per-edge: preds = sigmoid(relu(P[s]+Q[d]) . We2 + be2); be1 folded into P
// 32 lanes per edge, 16B loads
__global__ __launch_bounds__(256) void edge_pred_kernel(
  const unsigned short* __restrict__ P, const unsigned short* __restrict__ Q,
  const int* __restrict__ ei, const int* __restrict__ flag,
  const float* __restrict__ We2, const float* __restrict__ be2,
  float* __restrict__ preds, int E)
{
  int wid = blockIdx.x*8 + (threadIdx.x >> 5);
  int l = threadIdx.x & 31;
  if (wid >= E) return;
  int is64 = *flag;
  int s = edge_src(ei, wid, is64);
  int d = edge_dst(ei, wid, E, is64);
  us8 p8 = *(const us8*)&P[(size_t)s*HID + l*8];
  us8 q8 = *(const us8*)&Q[(size_t)d*HID + l*8];
  float4 w0 = *(const float4*)&We2[l*8];
  float4 w1 = *(const float4*)&We2[l*8 + 4];
  float part = 0.f;
  #pragma unroll
  for (int j = 0; j < 4; ++j)
    part = fmaf(fmaxf(b2f(p8[j]) + b2f(q8[j]), 0.f), (&w0.x)[j], part);
  #pragma unroll
  for (int j = 0; j < 4; ++j)
    part = fmaf(fmaxf(b2f(p8[4+j]) + b2f(q8[4+j]), 0.f), (&w1.x)[j], part);
  #pragma unroll
  for (int off = 16; off > 0; off >>= 1) part += __shfl_down(part, off, 32);
  if (l == 0) preds[wid] = sigmoidf_(part + be2[0]);
}

typedef const unsigned short* cus;
typedef const float* cf;

template<int MODE>
static void launch_f(const GJob* j, int nj, int M, hipStream_t s){
  dim3 g((M + 127)/128, nj), blk(512);
  mgemm5_kernel<MODE><<<g, blk, 0, s>>>(j[0], nj > 1 ? j[1] : j[0], nj > 2 ? j[2] : j[0], M);
}

extern "C" void kernel_launch(void* const* d_in, const int* in_sizes, int n_in,
                              void* d_out, int out_size, void* d_ws, size_t ws_size,
                              hipStream_t stream)
{
  const float* x    = (const float*)d_in[0];
  const int*   ei   = (const int*)  d_in[1];
  const float* Wx_l = (const float*)d_in[2];
  const float* bx_l = (const float*)d_in[3];
  const float* Wx_r = (const float*)d_in[4];
  const float* Wh_l = (const float*)d_in[5];
  const float* bh_l = (const float*)d_in[6];
  const float* Wh_r = (const float*)d_in[7];
  const float* Wb1  = (const float*)d_in[8];
  const float* bb1  = (const float*)d_in[9];
  const float* Wb2  = (const float*)d_in[10];
  const float* bb2  = (const float*)d_in[11];
  const float* We1  = (const float*)d_in[12];
  const float* be1  = (const float*)d_in[13];
  const float* We2  = (const float*)d_in[14];
  const float* be2  = (const float*)d_in[15];

  const int N = in_sizes[0] / HID;
  const int E = in_sizes[1] / 2;
  cf NUL = nullptr; cus NUB = nullptr;

  size_t off = 0;
  auto alloc = [&](size_t bytes) -> void* {
    void* p = (char*)d_ws + off;
    off += (bytes + 255) & ~(size_t)255;
    return p;
  };
  int*   deg_i   = (int*)  alloc((size_t)N*4);
  int*   cursor  = (int*)  alloc((size_t)N*4);
  int*   row_ptr = (int*)  alloc(((size_t)N+1)*4);
  int*   col_src = (int*)  alloc((size_t)E*4);
  float* inv_deg = (float*)alloc((size_t)N*4);
  int*   flag    = (int*)  alloc(256);
  float* brow    = (float*)alloc(1024);
  float* hrow    = (float*)alloc(1024);
  float* rowL1   = (float*)alloc(1024);
  float* rowR1   = (float*)alloc(1024);
  float* rowL2   = (float*)alloc(1024);
  float* rowR2   = (float*)alloc(1024);
  unsigned short* Wt = (unsigned short*)alloc((size_t)18*65536*2);   // bf16 [n][k] weights
  float* F1 = (float*)alloc((size_t)N*HID*4);    // z1 -> h1 -> hN2 (f32)
  unsigned short* b0 = (unsigned short*)alloc((size_t)N*HID*2);  // xb -> t1 -> h1 -> hN2 -> h2(bf16)
  unsigned short* b1 = (unsigned short*)alloc((size_t)N*HID*2);  // aggx -> agg ping-pong
  unsigned short* b2 = (unsigned short*)alloc((size_t)N*HID*2);  // xc0 -> t2 -> P
  unsigned short* b3 = (unsigned short*)alloc((size_t)N*HID*2);  // xc1 -> z2 -> Q
  unsigned short* b4 = (unsigned short*)alloc((size_t)N*HID*2);  // xc2 (bf16, persists)

  float* preds = (float*)d_out;
  float* H     = preds + E;          // final h2 (f32) output region

  auto WT = [&](int i) -> cus { return Wt + (size_t)i*65536; };
  // WT map: Wxl_j=j, Wxr_j=3+j, Whl_j=6+j, Whr_j=10+j, Wc1=14, Wbc=15, We1top=16, We1bot=17
  const float* bx0 = bx_l;  const float* bx1 = bx_l + 256; const float* bx2 = bx_l + 512;
  const float* bh1 = bh_l + 256;
  const float* bh2 = bh_l + 512; const float* bh3 = bh_l + 768;

  const int eb  = (E + 255)/256;
  const int nb4 = (N + 3)/4;
  const int n4b = (N*64 + 255)/256;

  auto mkjob = [&](cus A0,cus W0,cus A1,cus W1,
                   cf bias, cf Z, cf HN, int hnb,
                   cf mulmat, cf Df, cus Db, cus Zb,
                   float* oF, unsigned short* oB) -> GJob {
    GJob g;
    g.A0=A0; g.W0=W0; g.A1=A1; g.W1=W1;
    g.bias=bias; g.Z=Z; g.HN=HN; g.hn_bcast=hnb;
    g.mulmat=mulmat; g.Df=Df; g.Db=Db; g.Zb=Zb;
    g.outF=oF; g.outB=oB;
    return g;
  };

  // ---- CSR build ----
  hipMemsetAsync(deg_i, 0, (size_t)N*4, stream);
  hipMemsetAsync(cursor, 0, (size_t)N*4, stream);
  detect_kernel<<<1,256,0,stream>>>(ei, flag);
  count_kernel<<<eb,256,0,stream>>>(ei, flag, deg_i, E);
  scan_kernel<<<1,1024,0,stream>>>(deg_i, row_ptr, inv_deg, N);
  fill_kernel<<<eb,256,0,stream>>>(ei, flag, row_ptr, cursor, col_src, E);

  // ---- conversions + composite weights + constant rows ----
  conv_kernel<<<n4b,256,0,stream>>>(x, b0, N*64);                                 // xb -> b0
  wconv_kernel<<<dim3(18,256),256,0,stream>>>(Wx_l, Wx_r, Wh_l, Wh_r, Wb1, Wb2, We1, Wt);
  comp_kernel<<<256,256,0,stream>>>(Wh_l, Wb2, nullptr, (unsigned short*)WT(14)); // Wc1 = Whl0@Wb2
  comp_kernel<<<256,256,0,stream>>>(Wh_r, Wb2, Wb1,     (unsigned short*)WT(15)); // Wbc = Wb1 + Whr0@Wb2
  rowprep_kernel<<<1,256,0,stream>>>(bh_l, bb1, bb2, Wb2, Wh_l, Wh_r,
                                     brow, hrow, rowL1, rowR1, rowL2, rowR2);

  // ---- hoisted x-projections (computed ONCE, used by both layers) ----
  aggregate_b_kernel<<<nb4,256,0,stream>>>(b0, b1, row_ptr, col_src, inv_deg, N); // aggx -> b1
  {
    GJob j[3] = {
      // xc0 = aggx@Wxl0 + x@Wxr0 + bx0 -> b2 (bf16)
      mkjob(b1,WT(0), b0,WT(3), bx0, NUL,NUL,0, NUL,NUL,NUB,NUB, nullptr, b2),
      // xc1 = aggx@Wxl1 + x@Wxr1 + bx1 -> b3 (bf16)
      mkjob(b1,WT(1), b0,WT(4), bx1, NUL,NUL,0, NUL,NUL,NUB,NUB, nullptr, b3),
      // xc2 = aggx@Wxl2 + x@Wxr2 + bx2 -> b4 (bf16)
      mkjob(b1,WT(2), b0,WT(5), bx2, NUL,NUL,0, NUL,NUL,NUB,NUB, nullptr, b4)
    };
    launch_f<0>(j, 3, N, stream);
  }
  // x/aggx now dead -> b0/b1 reusable

  // ---- layer 1 (h = 0 specialization; t1/z1 are elementwise) ----
  l1_elem_kernel<<<n4b,256,0,stream>>>(b2, b3, deg_i, hrow, rowL1, rowR1,
                                       rowL2, rowR2, b0, F1, N);                  // t1->b0, z1->F1
  aggregate_b_kernel<<<nb4,256,0,stream>>>(b0, b1, row_ptr, col_src, inv_deg, N); // agg(t1) -> b1
  {
    // h1 = (1-z1)*hrow + z1*tanh(agg_t1@Whl3 + t1@Whr3 + xc2 + bh3) -> F1 (in-place), b0 (in-place)
    GJob j = mkjob(b1,WT(9), b0,WT(13), bh3, F1,hrow,1, NUL,NUL,b4,NUB, F1, b0);
    launch_f<3>(&j, 1, N, stream);
  }

  // ---- layer 2 ----
  aggregate_b_kernel<<<nb4,256,0,stream>>>(b0, b1, row_ptr, col_src, inv_deg, N); // agg(h1) -> b1
  {
    // hN2 = h1 + tanh(agg_h1@Wc1 + h1@Wbc + brow) -> F1 (in-place), b0 (in-place)
    GJob j = mkjob(b1,WT(14), b0,WT(15), brow, NUL,F1,0, NUL,NUL,NUB,NUB, F1, b0);
    launch_f<2>(&j, 1, N, stream);
  }
  aggregate_b_kernel<<<nb4,256,0,stream>>>(b0, b1, row_ptr, col_src, inv_deg, N); // agg(hN2) -> b1
  {
    GJob j[2] = {
      // t2 = sigmoid(agg@Whl1 + hN2@Whr1 + xc0 + bh1) * hN2 -> b2 (in-place Db)
      mkjob(b1,WT(7), b0,WT(11), bh1, NUL,NUL,0, F1,NUL,b2,NUB, nullptr, b2),
      // z2 = sigmoid(agg@Whl2 + hN2@Whr2 + xc1 + bh2) -> b3 (bf16, in-place Db)
      mkjob(b1,WT(8), b0,WT(12), bh2, NUL,NUL,0, NUL,NUL,b3,NUB, nullptr, b3)
    };
    launch_f<1>(j, 2, N, stream);
  }
  aggregate_b_kernel<<<nb4,256,0,stream>>>(b2, b1, row_ptr, col_src, inv_deg, N); // agg(t2) -> b1
  {
    // h2 = (1-z2)*hN2 + z2*tanh(agg_t2@Whl3 + t2@Whr3 + xc2 + bh3) -> H (f32), b0 (bf16)
    GJob j = mkjob(b1,WT(9), b2,WT(13), bh3, NUL,F1,0, NUL,NUL,b4,b3, H, b0);
    launch_f<3>(&j, 1, N, stream);
  }

  // ---- edge head ----
  {
    GJob j[2] = {
      mkjob(b0,WT(16), NUB,NUB, be1, NUL,NUL,0, NUL,NUL,NUB,NUB, nullptr, b2),  // P
      mkjob(b0,WT(17), NUB,NUB, NUL, NUL,NUL,0, NUL,NUL,NUB,NUB, nullptr, b3)   // Q
    };
    launch_f<0>(j, 2, N, stream);
  }
  edge_pred_kernel<<<(E+7)/8,256,0,stream>>>(b2, b3, ei, flag, We2, be2, preds, E);
}

// Round 11
// 1121.514 us; speedup vs baseline: 1.3511x; 1.3511x over previous
//
#include <hip/hip_runtime.h>
#include <math.h>

#define HID 256
#define LROW 40   // LDS row stride in bf16 elems (32 data + 8 pad) -> 80B

typedef __bf16 bf16x8 __attribute__((ext_vector_type(8)));
typedef float  f32x4  __attribute__((ext_vector_type(4)));
typedef unsigned short us8 __attribute__((ext_vector_type(8)));

__device__ __forceinline__ float sigmoidf_(float x){ return 1.0f/(1.0f + __expf(-x)); }
__device__ __forceinline__ unsigned short f2b(float f){
  __bf16 b = (__bf16)f; return __builtin_bit_cast(unsigned short, b);
}
__device__ __forceinline__ float b2f(unsigned short u){
  return (float)__builtin_bit_cast(__bf16, u);
}

// ---- edge index access: handles both int32 and int64 on-disk storage ----
__device__ __forceinline__ int edge_src(const int* ei, int e, int is64){
  return is64 ? ei[2*e] : ei[e];
}
__device__ __forceinline__ int edge_dst(const int* ei, int e, int E, int is64){
  return is64 ? ei[2*(E+e)] : ei[E+e];
}

__global__ void detect_kernel(const int* __restrict__ ei, int* __restrict__ flag){
  __shared__ int any;
  if (threadIdx.x == 0) any = 0;
  __syncthreads();
  if (ei[2*threadIdx.x + 1] != 0) atomicOr(&any, 1);
  __syncthreads();
  if (threadIdx.x == 0) *flag = any ? 0 : 1;   // 1 -> int64 storage
}

__global__ void count_kernel(const int* __restrict__ ei, const int* __restrict__ flag,
                             int* __restrict__ deg_i, int E){
  int e = blockIdx.x*blockDim.x + threadIdx.x;
  if (e >= E) return;
  int is64 = *flag;
  atomicAdd(&deg_i[edge_dst(ei,e,E,is64)], 1);
}

__global__ __launch_bounds__(1024) void scan_kernel(const int* __restrict__ deg_i,
  int* __restrict__ row_ptr, float* __restrict__ inv_deg, int N)
{
  __shared__ int wsum[16];
  __shared__ int carry_s;
  int tid = threadIdx.x, lane = tid & 63, wid = tid >> 6;
  if (tid == 0) carry_s = 0;
  __syncthreads();
  for (int base = 0; base < N; base += 1024){
    int i = base + tid;
    int v = (i < N) ? deg_i[i] : 0;
    int s = v;
    #pragma unroll
    for (int off = 1; off < 64; off <<= 1){
      int t = __shfl_up(s, off, 64);
      if (lane >= off) s += t;
    }
    if (lane == 63) wsum[wid] = s;
    __syncthreads();
    if (tid == 0){
      int run = 0;
      for (int w2 = 0; w2 < 16; ++w2){ int t = wsum[w2]; wsum[w2] = run; run += t; }
    }
    __syncthreads();
    int excl = carry_s + wsum[wid] + s - v;
    if (i < N){
      row_ptr[i] = excl;
      inv_deg[i] = 1.0f / fmaxf((float)v, 1.0f);
    }
    __syncthreads();
    if (tid == 1023) carry_s = excl + v;
    __syncthreads();
  }
  if (threadIdx.x == 0) row_ptr[N] = carry_s;
}

__global__ void fill_kernel(const int* __restrict__ ei, const int* __restrict__ flag,
                            const int* __restrict__ row_ptr, int* __restrict__ cursor,
                            int* __restrict__ col_src, int E){
  int e = blockIdx.x*blockDim.x + threadIdx.x;
  if (e >= E) return;
  int is64 = *flag;
  int d = edge_dst(ei,e,E,is64);
  int pos = atomicAdd(&cursor[d], 1);
  col_src[row_ptr[d] + pos] = edge_src(ei,e,is64);
}

// f32 -> bf16 conversion (vector of 4)
__global__ __launch_bounds__(256) void conv_kernel(const float* __restrict__ in,
                                                   unsigned short* __restrict__ out, int n4){
  int i = blockIdx.x*256 + threadIdx.x;
  if (i >= n4) return;
  float4 v = *(const float4*)&in[(size_t)i*4];
  ushort4 o; o.x=f2b(v.x); o.y=f2b(v.y); o.z=f2b(v.z); o.w=f2b(v.w);
  *(ushort4*)&out[(size_t)i*4] = o;
}

// weights: f32 [K][N] row-major -> bf16 [N][K] (transposed), 18 slabs of 256x256
__global__ __launch_bounds__(256) void wconv_kernel(
  const float* __restrict__ Wx_l, const float* __restrict__ Wx_r,
  const float* __restrict__ Wh_l, const float* __restrict__ Wh_r,
  const float* __restrict__ Wb1,  const float* __restrict__ Wb2,
  const float* __restrict__ We1,  unsigned short* __restrict__ Wt)
{
  int widx = blockIdx.x;       // 0..17
  int n = blockIdx.y;          // 0..255 (output row = W column)
  int k = threadIdx.x;         // 0..255
  const float* src;
  if      (widx < 3)  src = Wx_l + widx*65536;
  else if (widx < 6)  src = Wx_r + (widx-3)*65536;
  else if (widx < 10) src = Wh_l + (widx-6)*65536;
  else if (widx < 14) src = Wh_r + (widx-10)*65536;
  else if (widx == 14) src = Wb1;
  else if (widx == 15) src = Wb2;
  else                src = We1 + (widx-16)*65536;
  Wt[(size_t)widx*65536 + n*256 + k] = f2b(src[k*256 + n]);
}

// composite weight: dst[n][k] (bf16, transposed) = (A@B)[k][n] + add[k][n]
__global__ __launch_bounds__(256) void comp_kernel(
  const float* __restrict__ A, const float* __restrict__ B,
  const float* __restrict__ add, unsigned short* __restrict__ dst)
{
  __shared__ float col[256];
  int n = blockIdx.x, k = threadIdx.x;
  col[k] = B[k*256 + n];
  __syncthreads();
  float s = add ? add[k*256 + n] : 0.f;
  #pragma unroll 8
  for (int j = 0; j < 256; ++j) s = fmaf(A[k*256 + j], col[j], s);
  dst[n*256 + k] = f2b(s);
}

// mean aggregation over bf16 features: one wave per node, ushort4 per lane
__global__ __launch_bounds__(256) void aggregate_b_kernel(
    const unsigned short* __restrict__ X, unsigned short* __restrict__ out,
    const int* __restrict__ row_ptr, const int* __restrict__ col_src,
    const float* __restrict__ inv_deg, int N)
{
  int v = blockIdx.x*4 + (threadIdx.x >> 6);
  int lane = threadIdx.x & 63;
  if (v >= N) return;
  int beg = row_ptr[v], end = row_ptr[v+1];
  float a0=0.f, a1=0.f, a2=0.f, a3=0.f;
  int e = beg;
  for (; e + 8 <= end; e += 8){
    int sidx[8];
    #pragma unroll
    for (int t = 0; t < 8; ++t) sidx[t] = col_src[e + t];
    #pragma unroll
    for (int t = 0; t < 8; ++t){
      ushort4 u = *(const ushort4*)&X[(size_t)sidx[t]*HID + lane*4];
      a0 += b2f(u.x); a1 += b2f(u.y); a2 += b2f(u.z); a3 += b2f(u.w);
    }
  }
  for (; e < end; ++e){
    int s0 = col_src[e];
    ushort4 u = *(const ushort4*)&X[(size_t)s0*HID + lane*4];
    a0 += b2f(u.x); a1 += b2f(u.y); a2 += b2f(u.z); a3 += b2f(u.w);
  }
  float w = inv_deg[v];
  ushort4 o; o.x=f2b(a0*w); o.y=f2b(a1*w); o.z=f2b(a2*w); o.w=f2b(a3*w);
  *(ushort4*)&out[(size_t)v*HID + lane*4] = o;
}

// layer-1 constant rows (f32): brow = bb1+bb2+bh0@Wb2; hrow = tanh(brow); rowL/rowR for r,z
__global__ __launch_bounds__(256) void rowprep_kernel(
  const float* __restrict__ bh_l, const float* __restrict__ bb1, const float* __restrict__ bb2,
  const float* __restrict__ Wb2, const float* __restrict__ Wh_l, const float* __restrict__ Wh_r,
  float* __restrict__ brow, float* __restrict__ hrow,
  float* __restrict__ rowL1, float* __restrict__ rowR1,
  float* __restrict__ rowL2, float* __restrict__ rowR2)
{
  __shared__ float sh[256];
  __shared__ float sh2[256];
  int j = threadIdx.x;
  sh[j] = bh_l[j];                       // bh_l[0]
  __syncthreads();
  float acc = bb1[j] + bb2[j];
  for (int k = 0; k < 256; ++k) acc = fmaf(sh[k], Wb2[k*256 + j], acc);
  float hr = tanhf(acc);
  brow[j] = acc;
  hrow[j] = hr; sh2[j] = hr;
  __syncthreads();
  const float* Whl1 = Wh_l + 65536;  const float* Whr1 = Wh_r + 65536;
  const float* Whl2 = Wh_l + 131072; const float* Whr2 = Wh_r + 131072;
  float a1=0.f, b1=0.f, a2=0.f, b2v=0.f;
  for (int k = 0; k < 256; ++k){
    float hv = sh2[k];
    a1  = fmaf(hv, Whl1[k*256+j], a1);
    b1  = fmaf(hv, Whr1[k*256+j], b1);
    a2  = fmaf(hv, Whl2[k*256+j], a2);
    b2v = fmaf(hv, Whr2[k*256+j], b2v);
  }
  rowL1[j] = a1; rowR1[j] = b1 + bh_l[256 + j];
  rowL2[j] = a2; rowR2[j] = b2v + bh_l[512 + j];
}

// layer-1 elementwise (xc0/xc1 are hoisted x-projections, bf16):
// t1 = sigmoid(xc0 + g*rowL1 + rowR1)*hrow ; z1 = sigmoid(xc1 + g*rowL2 + rowR2)
__global__ __launch_bounds__(256) void l1_elem_kernel(
  const unsigned short* __restrict__ xc0, const unsigned short* __restrict__ xc1,
  const int* __restrict__ deg_i, const float* __restrict__ hrow,
  const float* __restrict__ rowL1, const float* __restrict__ rowR1,
  const float* __restrict__ rowL2, const float* __restrict__ rowR2,
  unsigned short* __restrict__ t1, float* __restrict__ z1, int N)
{
  int idx = blockIdx.x*256 + threadIdx.x;      // ushort4 index
  if (idx >= N*64) return;
  int v = idx >> 6, j4 = (idx & 63) * 4;
  float g = deg_i[v] > 0 ? 1.f : 0.f;
  ushort4 a = *(const ushort4*)&xc0[(size_t)idx*4];
  ushort4 b = *(const ushort4*)&xc1[(size_t)idx*4];
  float4 L1 = *(const float4*)&rowL1[j4];
  float4 R1 = *(const float4*)&rowR1[j4];
  float4 L2 = *(const float4*)&rowL2[j4];
  float4 R2 = *(const float4*)&rowR2[j4];
  float4 hr = *(const float4*)&hrow[j4];
  ushort4 t; float4 z;
  t.x = f2b(sigmoidf_(b2f(a.x) + g*L1.x + R1.x) * hr.x);
  t.y = f2b(sigmoidf_(b2f(a.y) + g*L1.y + R1.y) * hr.y);
  t.z = f2b(sigmoidf_(b2f(a.z) + g*L1.z + R1.z) * hr.z);
  t.w = f2b(sigmoidf_(b2f(a.w) + g*L1.w + R1.w) * hr.w);
  z.x = sigmoidf_(b2f(b.x) + g*L2.x + R2.x);
  z.y = sigmoidf_(b2f(b.y) + g*L2.y + R2.y);
  z.z = sigmoidf_(b2f(b.z) + g*L2.z + R2.z);
  z.w = sigmoidf_(b2f(b.w) + g*L2.w + R2.w);
  *(ushort4*)&t1[(size_t)idx*4] = t;
  *(float4*)&z1[(size_t)idx*4] = z;
}

// ---- fused MFMA GEMM: up to three jobs x two column-halves per dispatch ----
struct GJob {
  const unsigned short *A0,*W0,*A1,*W1;
  const float *bias,*Z,*HN;
  const float *mulmat;
  const unsigned short *Db,*Zb;
  float* outF; unsigned short* outB;
  int hn_bcast;
};

// 128-row x 128-col tile, 512 threads (8 waves 2x4; wave tile 64x32, acc[4][2]).
// blockIdx.y = job*2 + colhalf -> every job gets 782 blocks (>=3/CU TLP).
// RACE RULE: a job must never write (outB/outF) a buffer it reads as A operand
// (col-split blocks read all K of A while sibling writes). Epilogue-index reads
// (Db/Zb/Z/mulmat/HN) are tile-local and safe in-place.
// pre = sum_i Ai@Wi^T + bias + Db(bf16)
// MODE 0 LIN, 1 SIG(pre)*mulmat, 2 TANHADD: HN[idx]+tanh(pre), 3 GRU: (1-Z)*HN + Z*tanh(pre)
template<int MODE>
__global__ __launch_bounds__(512) void mgemm6_kernel(GJob j0, GJob j1, GJob j2, int M)
{
  __shared__ unsigned short Al[128*LROW];
  __shared__ unsigned short Wl[128*LROW];
  const int jidx = blockIdx.y >> 1;
  const GJob& J = (jidx == 0) ? j0 : ((jidx == 1) ? j1 : j2);
  const int col0 = (blockIdx.y & 1) * 128;
  const int tid  = threadIdx.x;
  const int lane = tid & 63, w = tid >> 6;     // 8 waves
  const int wr = w >> 2, wc = w & 3;           // 2 (row groups of 64) x 4 (col groups of 32)
  const int lane15 = lane & 15, laneq = (lane >> 4) * 8;
  const int row0 = blockIdx.x * 128;

  f32x4 acc[4][2];
  #pragma unroll
  for (int m = 0; m < 4; ++m)
    #pragma unroll
    for (int n = 0; n < 2; ++n) acc[m][n] = (f32x4)0.f;

  // compact pass list (up to 2 passes)
  const unsigned short* pa[2]; const unsigned short* pw[2];
  int np = 0;
  if (J.A0){ pa[np]=J.A0; pw[np]=J.W0; ++np; }
  if (J.A1){ pa[np]=J.A1; pw[np]=J.W1; ++np; }
  const int steps = np * 8;            // K=256, BK=32 -> always even

  // staging: row tid>>2 (0..127), 16B chunk (tid&3)*8 elems; A row + W row per thread
  const int strow = tid >> 2;
  const int koff  = (tid & 3) * 8;
  const int garow = (row0 + strow > M-1) ? (M-1) : (row0 + strow);
  const size_t abase = (size_t)garow*HID + koff;
  const size_t wbase = (size_t)(col0 + strow)*HID + koff;
  const int lidx = strow*LROW + koff;

  uint4 Ar0,Wr0, Ar1,Wr1;   // two static 2-deep prefetch sets
  auto loadR = [&](int sp, uint4& a, uint4& wv){
    const unsigned short* Ap = pa[sp >> 3];
    const unsigned short* Wp = pw[sp >> 3];
    const int k0 = (sp & 7) * 32;
    a  = *(const uint4*)(Ap + abase + k0);
    wv = *(const uint4*)(Wp + wbase + k0);
  };
  auto compute = [&](){
    bf16x8 af[4], bfr[2];
    #pragma unroll
    for (int m = 0; m < 4; ++m)
      af[m] = *(const bf16x8*)&Al[(wr*64 + m*16 + lane15)*LROW + laneq];
    #pragma unroll
    for (int n = 0; n < 2; ++n)
      bfr[n] = *(const bf16x8*)&Wl[(wc*32 + n*16 + lane15)*LROW + laneq];
    #pragma unroll
    for (int m = 0; m < 4; ++m)
      #pragma unroll
      for (int n = 0; n < 2; ++n)
        acc[m][n] = __builtin_amdgcn_mfma_f32_16x16x32_bf16(af[m], bfr[n], acc[m][n], 0, 0, 0);
  };

  loadR(0, Ar0,Wr0);
  loadR(1, Ar1,Wr1);
  for (int s = 0; s < steps; s += 2){
    __syncthreads();
    *(uint4*)&Al[lidx] = Ar0;
    *(uint4*)&Wl[lidx] = Wr0;
    __syncthreads();
    if (s + 2 < steps) loadR(s+2, Ar0,Wr0);
    compute();
    __syncthreads();
    *(uint4*)&Al[lidx] = Ar1;
    *(uint4*)&Wl[lidx] = Wr1;
    __syncthreads();
    if (s + 3 < steps) loadR(s+3, Ar1,Wr1);
    compute();
  }

  // epilogue: D[row][col]: col = lane&15, row = (lane>>4)*4 + r
  #pragma unroll
  for (int n = 0; n < 2; ++n){
    int gc = col0 + wc*32 + n*16 + lane15;
    float badd = J.bias ? J.bias[gc] : 0.f;
    float hnb = 0.f;
    if (MODE == 3 && J.hn_bcast) hnb = J.HN[gc];
    #pragma unroll
    for (int m = 0; m < 4; ++m){
      int rbse = row0 + wr*64 + m*16 + ((lane >> 4) << 2);
      #pragma unroll
      for (int r = 0; r < 4; ++r){
        int gr = rbse + r;
        if (gr >= M) continue;
        size_t idx = (size_t)gr*HID + gc;
        float p = acc[m][n][r] + badd;
        if (J.Db) p += b2f(J.Db[idx]);
        float v;
        if (MODE == 0) v = p;
        else if (MODE == 1){
          v = sigmoidf_(p);
          if (J.mulmat) v *= J.mulmat[idx];
        } else if (MODE == 2){
          v = J.HN[idx] + tanhf(p);
        } else {
          float z  = J.Z ? J.Z[idx] : b2f(J.Zb[idx]);
          float hv = J.hn_bcast ? hnb : J.HN[idx];
          v = (1.f - z)*hv + z*tanhf(p);
        }
        if (J.outF) J.outF[idx] = v;
        if (J.outB) J.outB[idx] = f2b(v);
      }
    }
  }
}

// per-edge: preds = sigmoid(relu(P[s]+Q[d]) . We2 + be2); be1 folded into P
// 32 lanes per edge, 16B loads
__global__ __launch_bounds__(256) void edge_pred_kernel(
  const unsigned short* __restrict__ P, const unsigned short* __restrict__ Q,
  const int* __restrict__ ei, const int* __restrict__ flag,
  const float* __restrict__ We2, const float* __restrict__ be2,
  float* __restrict__ preds, int E)
{
  int wid = blockIdx.x*8 + (threadIdx.x >> 5);
  int l = threadIdx.x & 31;
  if (wid >= E) return;
  int is64 = *flag;
  int s = edge_src(ei, wid, is64);
  int d = edge_dst(ei, wid, E, is64);
  us8 p8 = *(const us8*)&P[(size_t)s*HID + l*8];
  us8 q8 = *(const us8*)&Q[(size_t)d*HID + l*8];
  float4 w0 = *(const float4*)&We2[l*8];
  float4 w1 = *(const float4*)&We2[l*8 + 4];
  float part = 0.f;
  #pragma unroll
  for (int j = 0; j < 4; ++j)
    part = fmaf(fmaxf(b2f(p8[j]) + b2f(q8[j]), 0.f), (&w0.x)[j], part);
  #pragma unroll
  for (int j = 0; j < 4; ++j)
    part = fmaf(fmaxf(b2f(p8[4+j]) + b2f(q8[4+j]), 0.f), (&w1.x)[j], part);
  #pragma unroll
  for (int off = 16; off > 0; off >>= 1) part += __shfl_down(part, off, 32);
  if (l == 0) preds[wid] = sigmoidf_(part + be2[0]);
}

typedef const unsigned short* cus;
typedef const float* cf;

template<int MODE>
static void launch_f(const GJob* j, int nj, int M, hipStream_t s){
  dim3 g((M + 127)/128, nj*2), blk(512);
  mgemm6_kernel<MODE><<<g, blk, 0, s>>>(j[0], nj > 1 ? j[1] : j[0], nj > 2 ? j[2] : j[0], M);
}

extern "C" void kernel_launch(void* const* d_in, const int* in_sizes, int n_in,
                              void* d_out, int out_size, void* d_ws, size_t ws_size,
                              hipStream_t stream)
{
  const float* x    = (const float*)d_in[0];
  const int*   ei   = (const int*)  d_in[1];
  const float* Wx_l = (const float*)d_in[2];
  const float* bx_l = (const float*)d_in[3];
  const float* Wx_r = (const float*)d_in[4];
  const float* Wh_l = (const float*)d_in[5];
  const float* bh_l = (const float*)d_in[6];
  const float* Wh_r = (const float*)d_in[7];
  const float* Wb1  = (const float*)d_in[8];
  const float* bb1  = (const float*)d_in[9];
  const float* Wb2  = (const float*)d_in[10];
  const float* bb2  = (const float*)d_in[11];
  const float* We1  = (const float*)d_in[12];
  const float* be1  = (const float*)d_in[13];
  const float* We2  = (const float*)d_in[14];
  const float* be2  = (const float*)d_in[15];

  const int N = in_sizes[0] / HID;
  const int E = in_sizes[1] / 2;
  cf NUL = nullptr; cus NUB = nullptr;

  size_t off = 0;
  auto alloc = [&](size_t bytes) -> void* {
    void* p = (char*)d_ws + off;
    off += (bytes + 255) & ~(size_t)255;
    return p;
  };
  int*   deg_i   = (int*)  alloc((size_t)N*4);
  int*   cursor  = (int*)  alloc((size_t)N*4);
  int*   row_ptr = (int*)  alloc(((size_t)N+1)*4);
  int*   col_src = (int*)  alloc((size_t)E*4);
  float* inv_deg = (float*)alloc((size_t)N*4);
  int*   flag    = (int*)  alloc(256);
  float* brow    = (float*)alloc(1024);
  float* hrow    = (float*)alloc(1024);
  float* rowL1   = (float*)alloc(1024);
  float* rowR1   = (float*)alloc(1024);
  float* rowL2   = (float*)alloc(1024);
  float* rowR2   = (float*)alloc(1024);
  unsigned short* Wt = (unsigned short*)alloc((size_t)18*65536*2);   // bf16 [n][k] weights
  float* F1 = (float*)alloc((size_t)N*HID*4);    // z1 -> h1 -> hN2 (f32)
  unsigned short* b0 = (unsigned short*)alloc((size_t)N*HID*2);
  unsigned short* b1 = (unsigned short*)alloc((size_t)N*HID*2);
  unsigned short* b2 = (unsigned short*)alloc((size_t)N*HID*2);
  unsigned short* b3 = (unsigned short*)alloc((size_t)N*HID*2);
  unsigned short* b4 = (unsigned short*)alloc((size_t)N*HID*2);
  unsigned short* b5 = (unsigned short*)alloc((size_t)N*HID*2);

  float* preds = (float*)d_out;
  float* H     = preds + E;          // final h2 (f32) output region

  auto WT = [&](int i) -> cus { return Wt + (size_t)i*65536; };
  // WT map: Wxl_j=j, Wxr_j=3+j, Whl_j=6+j, Whr_j=10+j, Wc1=14, Wbc=15, We1top=16, We1bot=17
  const float* bx0 = bx_l;  const float* bx1 = bx_l + 256; const float* bx2 = bx_l + 512;
  const float* bh1 = bh_l + 256;
  const float* bh2 = bh_l + 512; const float* bh3 = bh_l + 768;

  const int eb  = (E + 255)/256;
  const int nb4 = (N + 3)/4;
  const int n4b = (N*64 + 255)/256;

  auto mkjob = [&](cus A0,cus W0,cus A1,cus W1,
                   cf bias, cf Z, cf HN, int hnb,
                   cf mulmat, cus Db, cus Zb,
                   float* oF, unsigned short* oB) -> GJob {
    GJob g;
    g.A0=A0; g.W0=W0; g.A1=A1; g.W1=W1;
    g.bias=bias; g.Z=Z; g.HN=HN; g.hn_bcast=hnb;
    g.mulmat=mulmat; g.Db=Db; g.Zb=Zb;
    g.outF=oF; g.outB=oB;
    return g;
  };

  // ---- CSR build ----
  hipMemsetAsync(deg_i, 0, (size_t)N*4, stream);
  hipMemsetAsync(cursor, 0, (size_t)N*4, stream);
  detect_kernel<<<1,256,0,stream>>>(ei, flag);
  count_kernel<<<eb,256,0,stream>>>(ei, flag, deg_i, E);
  scan_kernel<<<1,1024,0,stream>>>(deg_i, row_ptr, inv_deg, N);
  fill_kernel<<<eb,256,0,stream>>>(ei, flag, row_ptr, cursor, col_src, E);

  // ---- conversions + composite weights + constant rows ----
  conv_kernel<<<n4b,256,0,stream>>>(x, b0, N*64);                                 // xb -> b0
  wconv_kernel<<<dim3(18,256),256,0,stream>>>(Wx_l, Wx_r, Wh_l, Wh_r, Wb1, Wb2, We1, Wt);
  comp_kernel<<<256,256,0,stream>>>(Wh_l, Wb2, nullptr, (unsigned short*)WT(14)); // Wc1 = Whl0@Wb2
  comp_kernel<<<256,256,0,stream>>>(Wh_r, Wb2, Wb1,     (unsigned short*)WT(15)); // Wbc = Wb1 + Whr0@Wb2
  rowprep_kernel<<<1,256,0,stream>>>(bh_l, bb1, bb2, Wb2, Wh_l, Wh_r,
                                     brow, hrow, rowL1, rowR1, rowL2, rowR2);

  // ---- hoisted x-projections (computed ONCE, used by both layers) ----
  aggregate_b_kernel<<<nb4,256,0,stream>>>(b0, b1, row_ptr, col_src, inv_deg, N); // aggx -> b1
  {
    GJob j[3] = {
      // xc0 = aggx@Wxl0 + x@Wxr0 + bx0 -> b2 (bf16)
      mkjob(b1,WT(0), b0,WT(3), bx0, NUL,NUL,0, NUL,NUB,NUB, nullptr, b2),
      // xc1 = aggx@Wxl1 + x@Wxr1 + bx1 -> b3 (bf16)
      mkjob(b1,WT(1), b0,WT(4), bx1, NUL,NUL,0, NUL,NUB,NUB, nullptr, b3),
      // xc2 = aggx@Wxl2 + x@Wxr2 + bx2 -> b4 (bf16)
      mkjob(b1,WT(2), b0,WT(5), bx2, NUL,NUL,0, NUL,NUB,NUB, nullptr, b4)
    };
    launch_f<0>(j, 3, N, stream);    // grid (391,6)
  }
  // x/aggx dead -> b0/b1 reusable

  // ---- layer 1 (h = 0 specialization; t1/z1 are elementwise) ----
  l1_elem_kernel<<<n4b,256,0,stream>>>(b2, b3, deg_i, hrow, rowL1, rowR1,
                                       rowL2, rowR2, b0, F1, N);                  // t1->b0, z1->F1
  aggregate_b_kernel<<<nb4,256,0,stream>>>(b0, b1, row_ptr, col_src, inv_deg, N); // agg(t1) -> b1
  {
    // h1 = (1-z1)*hrow + z1*tanh(agg_t1@Whl3 + t1@Whr3 + xc2 + bh3) -> F1 (idx-local), b5 (A-safe)
    GJob j = mkjob(b1,WT(9), b0,WT(13), bh3, F1,hrow,1, NUL,b4,NUB, F1, b5);
    launch_f<3>(&j, 1, N, stream);   // grid (391,2)
  }

  // ---- layer 2 ----
  aggregate_b_kernel<<<nb4,256,0,stream>>>(b5, b0, row_ptr, col_src, inv_deg, N); // agg(h1) -> b0
  {
    // hN2 = h1 + tanh(agg_h1@Wc1 + h1@Wbc + brow) -> F1 (idx-local), b1 (A-safe)
    GJob j = mkjob(b0,WT(14), b5,WT(15), brow, NUL,F1,0, NUL,NUB,NUB, F1, b1);
    launch_f<2>(&j, 1, N, stream);
  }
  aggregate_b_kernel<<<nb4,256,0,stream>>>(b1, b0, row_ptr, col_src, inv_deg, N); // agg(hN2) -> b0
  {
    GJob j[2] = {
      // t2 = sigmoid(agg@Whl1 + hN2@Whr1 + xc0 + bh1) * hN2 -> b5 (A-safe; Db=b2 idx-local)
      mkjob(b0,WT(7), b1,WT(11), bh1, NUL,NUL,0, F1,b2,NUB, nullptr, b5),
      // z2 = sigmoid(agg@Whl2 + hN2@Whr2 + xc1 + bh2) -> b3 (idx-local in-place Db)
      mkjob(b0,WT(8), b1,WT(12), bh2, NUL,NUL,0, NUL,b3,NUB, nullptr, b3)
    };
    launch_f<1>(j, 2, N, stream);    // grid (391,4)
  }
  aggregate_b_kernel<<<nb4,256,0,stream>>>(b5, b0, row_ptr, col_src, inv_deg, N); // agg(t2) -> b0
  {
    // h2 = (1-z2)*hN2 + z2*tanh(agg_t2@Whl3 + t2@Whr3 + xc2 + bh3) -> H (f32), b1 (A-safe)
    GJob j = mkjob(b0,WT(9), b5,WT(13), bh3, NUL,F1,0, NUL,b4,b3, H, b1);
    launch_f<3>(&j, 1, N, stream);
  }

  // ---- edge head ----
  {
    GJob j[2] = {
      mkjob(b1,WT(16), NUB,NUB, be1, NUL,NUL,0, NUL,NUB,NUB, nullptr, b2),  // P = h2@We1_top + be1
      mkjob(b1,WT(17), NUB,NUB, NUL, NUL,NUL,0, NUL,NUB,NUB, nullptr, b5)   // Q = h2@We1_bot
    };
    launch_f<0>(j, 2, N, stream);    // grid (391,4)
  }
  edge_pred_kernel<<<(E+7)/8,256,0,stream>>>(b2, b5, ei, flag, We2, be2, preds, E);
}